// Round 1
// baseline (1032.362 us; speedup 1.0000x reference)
//
#include <hip/hip_runtime.h>
#include <cstdint>
#include <cstddef>

// Problem dims (fixed by harness): x[2,2048,4096] fp32, qweight[16384,4096] int32(int8 vals),
// scales[16384,128] fp32 (per-32 block), bias[16384] fp32. out = x @ W^T + b, fp32.
#define M_DIM 4096
#define N_DIM 16384
#define K_DIM 4096
#define QBLK 32

constexpr int BM = 128, BN = 128, BK = 64;
constexpr int NT = K_DIM / BK;          // 64 K-steps

typedef __bf16 bf16x8 __attribute__((ext_vector_type(8)));
typedef float  f32x4  __attribute__((ext_vector_type(4)));
typedef unsigned short u16x8 __attribute__((ext_vector_type(8)));

// fp32 -> bf16 (RNE) as raw bits
__device__ __forceinline__ unsigned short f2bf(float f) {
    unsigned int x = __builtin_bit_cast(unsigned int, f);
    x += 0x7fffu + ((x >> 16) & 1u);
    return (unsigned short)(x >> 16);
}

// async global->LDS, 16B per lane. LDS dest must be wave-uniform base (HW adds lane*16).
__device__ __forceinline__ void gload16(const void* g, void* l) {
    __builtin_amdgcn_global_load_lds((__attribute__((address_space(1))) unsigned int*)(g),
                                     (__attribute__((address_space(3))) unsigned int*)(l),
                                     16, 0, 0);
}

// ---------------- pre-pass: x fp32 -> bf16 ----------------
__global__ __launch_bounds__(256) void cvt_x_kernel(const float* __restrict__ x,
                                                    unsigned short* __restrict__ o) {
    const size_t total = (size_t)M_DIM * K_DIM / 8;   // 16B output chunks
    for (size_t i = (size_t)blockIdx.x * 256 + threadIdx.x; i < total;
         i += (size_t)gridDim.x * 256) {
        const float4* src = (const float4*)(x + i * 8);
        float4 a0 = src[0], a1 = src[1];
        u16x8 v;
        v[0] = f2bf(a0.x); v[1] = f2bf(a0.y); v[2] = f2bf(a0.z); v[3] = f2bf(a0.w);
        v[4] = f2bf(a1.x); v[5] = f2bf(a1.y); v[6] = f2bf(a1.z); v[7] = f2bf(a1.w);
        *(u16x8*)(o + i * 8) = v;
    }
}

// ---------------- pre-pass: W dequant int8(int32)+scale -> bf16 ----------------
__global__ __launch_bounds__(256) void dequant_w_kernel(const int* __restrict__ q,
                                                        const float* __restrict__ s,
                                                        unsigned short* __restrict__ o) {
    const size_t total = (size_t)N_DIM * K_DIM / 8;   // 8 elems per thread-iter
    for (size_t i = (size_t)blockIdx.x * 256 + threadIdx.x; i < total;
         i += (size_t)gridDim.x * 256) {
        const int4* src = (const int4*)(q + i * 8);
        int4 q0 = src[0], q1 = src[1];
        float sc = s[i >> 2];                         // (i*8)/32 ; K%32==0 so flat idx works
        u16x8 v;
        v[0] = f2bf((float)q0.x * sc); v[1] = f2bf((float)q0.y * sc);
        v[2] = f2bf((float)q0.z * sc); v[3] = f2bf((float)q0.w * sc);
        v[4] = f2bf((float)q1.x * sc); v[5] = f2bf((float)q1.y * sc);
        v[6] = f2bf((float)q1.z * sc); v[7] = f2bf((float)q1.w * sc);
        *(u16x8*)(o + i * 8) = v;
    }
}

// ---------------- main GEMM ----------------
// C[M,N] = A[M,K] * B[N,K]^T ; A,B bf16 row-major in K.
// 128x128 tile, BK=64, 4 waves (2x2), each wave 64x64 via 4x4 frags of 16x16x32 MFMA.
// LDS: 2 buffers x (A 16KB + B 16KB) = 64KB. 16B-chunk XOR swizzle (chunk ^= row&7) to
// kill the stride-128B bank conflict; applied on the *global source* for the direct
// (global_load_lds) path and on the ds_write address for the fused path.
template <bool FUSED>
__global__ __launch_bounds__(256, 2) void gemm_kernel(
    const unsigned short* __restrict__ Abf, const unsigned short* __restrict__ Bbf,
    const float* __restrict__ Xf, const int* __restrict__ Qw, const float* __restrict__ Sc,
    const float* __restrict__ bias, float* __restrict__ out) {

    __shared__ char smem[2 * 32768];

    const int t  = threadIdx.x;
    const int l  = t & 63;
    const int w  = t >> 6;         // wave 0..3
    const int wm = w >> 1, wn = w & 1;
    const int rowA0 = blockIdx.y * BM;     // m tile base
    const int colB0 = blockIdx.x * BN;     // n tile base

    // ---- staging geometry: tile = 16 chunks of 1KB; chunk c covers rows c*8..c*8+7.
    // lane l -> LDS slot row (c*8 + (l>>3)), 16B-col (l&7). Slot holds logical col (l&7)^(l>>3).
    const int lr   = l >> 3;
    const int sXor = (l & 7) ^ lr;         // logical 16B-chunk this lane fetches

    const char* aSrc[4]; const char* bSrc[4];
    const float* aSrcF[4]; const int* bSrcQ[4]; const float* bSrcS[4];
    if constexpr (!FUSED) {
        #pragma unroll
        for (int j = 0; j < 4; ++j) {
            int c  = w * 4 + j;
            int ra = rowA0 + c * 8 + lr;
            int rb = colB0 + c * 8 + lr;
            aSrc[j] = (const char*)Abf + (size_t)ra * (K_DIM * 2) + (size_t)sXor * 16;
            bSrc[j] = (const char*)Bbf + (size_t)rb * (K_DIM * 2) + (size_t)sXor * 16;
        }
    } else {
        #pragma unroll
        for (int j = 0; j < 4; ++j) {
            int c  = w * 4 + j;
            int ra = rowA0 + c * 8 + lr;
            int rb = colB0 + c * 8 + lr;
            aSrcF[j] = Xf + (size_t)ra * K_DIM + sXor * 8;
            bSrcQ[j] = Qw + (size_t)rb * K_DIM + sXor * 8;
            bSrcS[j] = Sc + (size_t)rb * (K_DIM / QBLK) + (sXor >> 2);
        }
    }

    // ---- ds_read bases (per-lane), XOR-swizzled: addr = row*128 + (chunk ^ (row&7))*16
    const int lrow = l & 15;
    const int l47  = l >> 4;
    const int lx   = l & 7;
    const unsigned raB0 = (unsigned)((wm * 64 + lrow) * 128 + ((l47 ^ lx) * 16));
    const unsigned raB1 = (unsigned)((wm * 64 + lrow) * 128 + (((4 | l47) ^ lx) * 16));
    const unsigned rbB0 = (unsigned)(16384 + (wn * 64 + lrow) * 128 + ((l47 ^ lx) * 16));
    const unsigned rbB1 = (unsigned)(16384 + (wn * 64 + lrow) * 128 + (((4 | l47) ^ lx) * 16));

    float fA[4][8]; int qB[4][8]; float sB[4];

    auto stage_direct = [&](int bsel) {
        #pragma unroll
        for (int j = 0; j < 4; ++j) {
            gload16(aSrc[j], &smem[bsel * 32768 + (w * 4 + j) * 1024]);
            aSrc[j] += BK * 2;
        }
        #pragma unroll
        for (int j = 0; j < 4; ++j) {
            gload16(bSrc[j], &smem[bsel * 32768 + 16384 + (w * 4 + j) * 1024]);
            bSrc[j] += BK * 2;
        }
    };
    auto stage_fused_load = [&]() {
        #pragma unroll
        for (int j = 0; j < 4; ++j) {
            float4 a0 = ((const float4*)aSrcF[j])[0];
            float4 a1 = ((const float4*)aSrcF[j])[1];
            fA[j][0] = a0.x; fA[j][1] = a0.y; fA[j][2] = a0.z; fA[j][3] = a0.w;
            fA[j][4] = a1.x; fA[j][5] = a1.y; fA[j][6] = a1.z; fA[j][7] = a1.w;
            aSrcF[j] += BK;
            int4 b0 = ((const int4*)bSrcQ[j])[0];
            int4 b1 = ((const int4*)bSrcQ[j])[1];
            qB[j][0] = b0.x; qB[j][1] = b0.y; qB[j][2] = b0.z; qB[j][3] = b0.w;
            qB[j][4] = b1.x; qB[j][5] = b1.y; qB[j][6] = b1.z; qB[j][7] = b1.w;
            bSrcQ[j] += BK;
            sB[j] = *bSrcS[j];
            bSrcS[j] += BK / QBLK;
        }
    };
    auto stage_fused_write = [&](int bsel) {
        #pragma unroll
        for (int j = 0; j < 4; ++j) {
            u16x8 va, vb;
            #pragma unroll
            for (int e = 0; e < 8; ++e) va[e] = f2bf(fA[j][e]);
            #pragma unroll
            for (int e = 0; e < 8; ++e) vb[e] = f2bf((float)qB[j][e] * sB[j]);
            *(u16x8*)(&smem[bsel * 32768 + (w * 4 + j) * 1024 + l * 16]) = va;
            *(u16x8*)(&smem[bsel * 32768 + 16384 + (w * 4 + j) * 1024 + l * 16]) = vb;
        }
    };

    f32x4 acc[4][4] = {};

    if constexpr (!FUSED) { stage_direct(0); }
    else { stage_fused_load(); stage_fused_write(0); }
    __syncthreads();

    int bsel = 0;
    for (int kt = 0; kt < NT; ++kt) {
        const bool pre = (kt + 1 < NT);
        if constexpr (!FUSED) { if (pre) stage_direct(bsel ^ 1); }
        else { if (pre) stage_fused_load(); }   // issue loads early (T14)

        const unsigned boff = (unsigned)(bsel * 32768);
        #pragma unroll
        for (int kk = 0; kk < 2; ++kk) {
            bf16x8 av[4], bv[4];
            const unsigned ra = (kk ? raB1 : raB0) + boff;
            const unsigned rb = (kk ? rbB1 : rbB0) + boff;
            #pragma unroll
            for (int mf = 0; mf < 4; ++mf) av[mf] = *(const bf16x8*)(&smem[ra + mf * 2048]);
            #pragma unroll
            for (int nf = 0; nf < 4; ++nf) bv[nf] = *(const bf16x8*)(&smem[rb + nf * 2048]);
            #pragma unroll
            for (int mf = 0; mf < 4; ++mf)
                #pragma unroll
                for (int nf = 0; nf < 4; ++nf)
                    acc[mf][nf] = __builtin_amdgcn_mfma_f32_16x16x32_bf16(
                        av[mf], bv[nf], acc[mf][nf], 0, 0, 0);
        }

        if constexpr (FUSED) { if (pre) stage_fused_write(bsel ^ 1); }  // vmcnt waits here
        __syncthreads();
        bsel ^= 1;
    }

    // ---- epilogue: C/D layout col=lane&15, row=(lane>>4)*4+reg
    const int orow0 = rowA0 + wm * 64 + l47 * 4;
    const int ocol0 = colB0 + wn * 64 + lrow;
    #pragma unroll
    for (int nf = 0; nf < 4; ++nf) {
        const float bv = bias[ocol0 + nf * 16];
        #pragma unroll
        for (int mf = 0; mf < 4; ++mf) {
            f32x4 v = acc[mf][nf];
            #pragma unroll
            for (int j = 0; j < 4; ++j) {
                const int r = orow0 + mf * 16 + j;
                out[(size_t)r * N_DIM + (ocol0 + nf * 16)] = v[j] + bv;
            }
        }
    }
}

extern "C" void kernel_launch(void* const* d_in, const int* in_sizes, int n_in,
                              void* d_out, int out_size, void* d_ws, size_t ws_size,
                              hipStream_t stream) {
    const float* x    = (const float*)d_in[0];
    const int*   qw   = (const int*)d_in[1];
    const float* sc   = (const float*)d_in[2];
    const float* bias = (const float*)d_in[3];
    float* out = (float*)d_out;

    const size_t need = ((size_t)M_DIM * K_DIM + (size_t)N_DIM * K_DIM) * 2;  // 160 MiB
    dim3 grid(N_DIM / BN, M_DIM / BM);   // (128, 32)

    if (ws_size >= need) {
        unsigned short* xb = (unsigned short*)d_ws;
        unsigned short* wb = xb + (size_t)M_DIM * K_DIM;
        cvt_x_kernel<<<dim3(1024), dim3(256), 0, stream>>>(x, xb);
        dequant_w_kernel<<<dim3(2048), dim3(256), 0, stream>>>(qw, sc, wb);
        gemm_kernel<false><<<grid, dim3(256), 0, stream>>>(xb, wb, nullptr, nullptr, nullptr,
                                                           bias, out);
    } else {
        gemm_kernel<true><<<grid, dim3(256), 0, stream>>>(nullptr, nullptr, x, qw, sc,
                                                          bias, out);
    }
}

// Round 3
// 923.736 us; speedup vs baseline: 1.1176x; 1.1176x over previous
//
#include <hip/hip_runtime.h>
#include <cstdint>
#include <cstddef>

// x[4096,4096] fp32, qweight[16384,4096] int32(int8 vals), scales[16384,128] fp32,
// bias[16384] fp32. out[4096,16384] = x @ W^T + b, fp32.
#define M_DIM 4096
#define N_DIM 16384
#define K_DIM 4096
#define QBLK 32

typedef __bf16 bf16x8 __attribute__((ext_vector_type(8)));
typedef float  f32x4  __attribute__((ext_vector_type(4)));
typedef unsigned short u16x8 __attribute__((ext_vector_type(8)));

__device__ __forceinline__ unsigned short f2bf(float f) {
    unsigned int x = __builtin_bit_cast(unsigned int, f);
    x += 0x7fffu + ((x >> 16) & 1u);
    return (unsigned short)(x >> 16);
}

__device__ __forceinline__ void gload16(const void* g, void* l) {
    __builtin_amdgcn_global_load_lds((__attribute__((address_space(1))) unsigned int*)(g),
                                     (__attribute__((address_space(3))) unsigned int*)(l),
                                     16, 0, 0);
}

// ---------------- pre-pass: x fp32 -> bf16 ----------------
__global__ __launch_bounds__(256) void cvt_x_kernel(const float* __restrict__ x,
                                                    unsigned short* __restrict__ o) {
    const size_t total = (size_t)M_DIM * K_DIM / 8;
    for (size_t i = (size_t)blockIdx.x * 256 + threadIdx.x; i < total;
         i += (size_t)gridDim.x * 256) {
        const float4* src = (const float4*)(x + i * 8);
        float4 a0 = src[0], a1 = src[1];
        u16x8 v;
        v[0] = f2bf(a0.x); v[1] = f2bf(a0.y); v[2] = f2bf(a0.z); v[3] = f2bf(a0.w);
        v[4] = f2bf(a1.x); v[5] = f2bf(a1.y); v[6] = f2bf(a1.z); v[7] = f2bf(a1.w);
        *(u16x8*)(o + i * 8) = v;
    }
}

// ---------------- pre-pass: W dequant -> bf16 ----------------
__global__ __launch_bounds__(256) void dequant_w_kernel(const int* __restrict__ q,
                                                        const float* __restrict__ s,
                                                        unsigned short* __restrict__ o) {
    const size_t total = (size_t)N_DIM * K_DIM / 8;
    for (size_t i = (size_t)blockIdx.x * 256 + threadIdx.x; i < total;
         i += (size_t)gridDim.x * 256) {
        const int4* src = (const int4*)(q + i * 8);
        int4 q0 = src[0], q1 = src[1];
        float sc = s[i >> 2];
        u16x8 v;
        v[0] = f2bf((float)q0.x * sc); v[1] = f2bf((float)q0.y * sc);
        v[2] = f2bf((float)q0.z * sc); v[3] = f2bf((float)q0.w * sc);
        v[4] = f2bf((float)q1.x * sc); v[5] = f2bf((float)q1.y * sc);
        v[6] = f2bf((float)q1.z * sc); v[7] = f2bf((float)q1.w * sc);
        *(u16x8*)(o + i * 8) = v;
    }
}

// ---------------- main GEMM: 256x256 tile, BK=64, 8 waves, 8-phase counted-vmcnt ----
// Wave (wm=w>>2, wn=w&3) owns rows {mh*128 + wm*64 + mf*16} x cols {nh*128 + wn*32 + nf*16}
// so each quadrant phase (mh,nh) touches exactly one A-half and one B-half of LDS.
// LDS: 2 dbuf x (A: 2 halves x 16KB, B: 2 halves x 16KB) = 128 KiB.
// Half-tile = 128 rows x 64 cols bf16, row stride 128B, 16B-chunk XOR swizzle
// (slot = chunk ^ (row&7)) applied on stage SOURCE and ds_read (both-sides rule #21).
// Pipeline: tile t stages A1,B1 of t+1 and A0,B0 of t+2; vmcnt(4) once per K-tile.
__global__ __launch_bounds__(512, 2) void gemm256(
    const unsigned short* __restrict__ Abf, const unsigned short* __restrict__ Bbf,
    const float* __restrict__ bias, float* __restrict__ out) {

    __shared__ char smem[131072];

    const int t  = threadIdx.x;
    const int l  = t & 63;
    const int w  = t >> 6;       // wave 0..7
    const int wm = w >> 2;       // 0..1
    const int wn = w & 3;        // 0..3

    // XCD-aware bijective swizzle (nwg = 1024, %8 == 0)
    const int bid = blockIdx.y * 64 + blockIdx.x;
    const int wg  = (bid & 7) * 128 + (bid >> 3);
    const int bx  = wg & 63;
    const int by  = wg >> 6;
    const int tileM = by * 256;
    const int tileN = bx * 256;

    // staging: thread covers row sr (within 64-row j-half), swizzled chunk cs
    const int sr = w * 8 + (l >> 3);
    const int cs = (l & 7) ^ (l >> 3);
    const char* aP = (const char*)Abf + (size_t)(tileM + sr) * (K_DIM * 2) + cs * 16;
    const char* bP = (const char*)Bbf + (size_t)(tileN + sr) * (K_DIM * 2) + cs * 16;
    const int wq = w * 1024;

    // ds_read per-lane offsets (within a 16KB half): addr = row*128 + (chunk^(row&7))*16
    const int lrow = l & 15, l47 = l >> 4;
    const int sw = lrow & 7;
    const unsigned c0 = (unsigned)((l47 ^ sw) * 16);
    const unsigned c1 = (unsigned)(((4 + l47) ^ sw) * 16);
    const unsigned offA0 = (unsigned)((wm * 64 + lrow) * 128) + c0;
    const unsigned offA1 = (unsigned)((wm * 64 + lrow) * 128) + c1;
    const unsigned offB0 = (unsigned)((wn * 32 + lrow) * 128) + c0;
    const unsigned offB1 = (unsigned)((wn * 32 + lrow) * 128) + c1;

    bf16x8 avr[4][2];        // A frags (mf within half, kk), reused across mh
    bf16x8 bvr[2][2][2];     // B frags (nh, nf within half, kk), both nh live
    f32x4  acc[2][4][2][2] = {};   // (mh, mf, nh, nf)

#define ST_A(H, KT, DB) do { \
    const char* g_ = aP + (size_t)(H) * 1048576u + (unsigned)(KT) * 128u; \
    char* d_ = smem + (DB) * 65536 + (H) * 16384 + wq; \
    gload16(g_, d_); gload16(g_ + 524288, d_ + 8192); } while (0)

#define ST_B(H, KT, DB) do { \
    const char* g_ = bP + (size_t)(H) * 1048576u + (unsigned)(KT) * 128u; \
    char* d_ = smem + (DB) * 65536 + 32768 + (H) * 16384 + wq; \
    gload16(g_, d_); gload16(g_ + 8192 * 64, d_ + 8192); } while (0)

#define RD_A(DB, MH) do { \
    const char* b_ = smem + (DB) * 65536 + (MH) * 16384; \
    _Pragma("unroll") for (int mf_ = 0; mf_ < 4; ++mf_) { \
        avr[mf_][0] = *(const bf16x8*)(b_ + offA0 + mf_ * 2048); \
        avr[mf_][1] = *(const bf16x8*)(b_ + offA1 + mf_ * 2048); } } while (0)

#define RD_B(DB, NH) do { \
    const char* b_ = smem + (DB) * 65536 + 32768 + (NH) * 16384; \
    _Pragma("unroll") for (int nf_ = 0; nf_ < 2; ++nf_) { \
        bvr[NH][nf_][0] = *(const bf16x8*)(b_ + offB0 + nf_ * 2048); \
        bvr[NH][nf_][1] = *(const bf16x8*)(b_ + offB1 + nf_ * 2048); } } while (0)

#define MMQ(MH, NH) do { __builtin_amdgcn_s_setprio(1); \
    _Pragma("unroll") for (int mf_ = 0; mf_ < 4; ++mf_) \
    _Pragma("unroll") for (int nf_ = 0; nf_ < 2; ++nf_) \
    _Pragma("unroll") for (int kk_ = 0; kk_ < 2; ++kk_) \
        acc[MH][mf_][NH][nf_] = __builtin_amdgcn_mfma_f32_16x16x32_bf16( \
            avr[mf_][kk_], bvr[NH][nf_][kk_], acc[MH][mf_][NH][nf_], 0, 0, 0); \
    __builtin_amdgcn_s_setprio(0); } while (0)

#define BAR __builtin_amdgcn_s_barrier()
#define LGKM do { asm volatile("s_waitcnt lgkmcnt(0)" ::: "memory"); \
                  __builtin_amdgcn_sched_barrier(0); } while (0)
#define VMC(N) asm volatile("s_waitcnt vmcnt(" #N ")" ::: "memory")

    // prologue: tile0 complete (8 loads) + A0,B0 of tile1 in flight (4 loads)
    ST_A(0, 0, 0); ST_A(1, 0, 0); ST_B(0, 0, 0); ST_B(1, 0, 0);
    ST_A(0, 1, 1); ST_B(0, 1, 1);
    VMC(4); BAR;

    for (int i = 0; i < 32; ++i) {
        const int k0 = 2 * i;
        const int ka = (k0 + 1) & 63;
        const int kb = (k0 + 2) & 63;
        const int kc = (k0 + 3) & 63;
        // ---- tile k0 (buf0): stage A1,B1 of ka->buf1, A0,B0 of kb->buf0
        RD_A(0, 0); RD_B(0, 0); ST_A(1, ka, 1); BAR; LGKM; MMQ(0, 0); BAR;
        RD_B(0, 1);             ST_B(1, ka, 1); BAR; LGKM; MMQ(0, 1); BAR;
        RD_A(0, 1);             ST_A(0, kb, 0); BAR; LGKM; MMQ(1, 0); BAR;
                                ST_B(0, kb, 0); BAR;       MMQ(1, 1); VMC(4); BAR;
        // ---- tile ka (buf1): stage A1,B1 of kb->buf0, A0,B0 of kc->buf1
        RD_A(1, 0); RD_B(1, 0); ST_A(1, kb, 0); BAR; LGKM; MMQ(0, 0); BAR;
        RD_B(1, 1);             ST_B(1, kb, 0); BAR; LGKM; MMQ(0, 1); BAR;
        RD_A(1, 1);             ST_A(0, kc, 1); BAR; LGKM; MMQ(1, 0); BAR;
                                ST_B(0, kc, 1); BAR;       MMQ(1, 1); VMC(4); BAR;
    }

    VMC(0);   // drain the tail prefetches before epilogue / endpgm

    // epilogue: C/D layout col = lane&15, row = (lane>>4)*4 + reg
    #pragma unroll
    for (int mh = 0; mh < 2; ++mh)
    #pragma unroll
    for (int nh = 0; nh < 2; ++nh)
    #pragma unroll
    for (int nf = 0; nf < 2; ++nf) {
        const int col = tileN + nh * 128 + wn * 32 + nf * 16 + lrow;
        const float bv = bias[col];
        #pragma unroll
        for (int mf = 0; mf < 4; ++mf) {
            const int row0 = tileM + mh * 128 + wm * 64 + mf * 16 + l47 * 4;
            f32x4 v = acc[mh][mf][nh][nf];
            #pragma unroll
            for (int j = 0; j < 4; ++j)
                out[(size_t)(row0 + j) * N_DIM + col] = v[j] + bv;
        }
    }
#undef ST_A
#undef ST_B
#undef RD_A
#undef RD_B
#undef MMQ
#undef BAR
#undef LGKM
#undef VMC
}

// ---------------- fallback fused 128x128 kernel (only if ws too small) ----------------
__global__ __launch_bounds__(256, 2) void gemm_fused(
    const float* __restrict__ Xf, const int* __restrict__ Qw, const float* __restrict__ Sc,
    const float* __restrict__ bias, float* __restrict__ out) {

    __shared__ char smem[2 * 32768];
    const int t = threadIdx.x;
    const int l = t & 63;
    const int w = t >> 6;
    const int wm = w >> 1, wn = w & 1;
    const int rowA0 = blockIdx.y * 128;
    const int colB0 = blockIdx.x * 128;

    const int lr = l >> 3;
    const int sXor = (l & 7) ^ lr;

    const float* aSrcF[4]; const int* bSrcQ[4]; const float* bSrcS[4];
    #pragma unroll
    for (int j = 0; j < 4; ++j) {
        int c = w * 4 + j;
        aSrcF[j] = Xf + (size_t)(rowA0 + c * 8 + lr) * K_DIM + sXor * 8;
        bSrcQ[j] = Qw + (size_t)(colB0 + c * 8 + lr) * K_DIM + sXor * 8;
        bSrcS[j] = Sc + (size_t)(colB0 + c * 8 + lr) * (K_DIM / QBLK) + (sXor >> 2);
    }

    const int lrow = l & 15, l47 = l >> 4, lx = l & 7;
    const unsigned raB0 = (unsigned)((wm * 64 + lrow) * 128 + ((l47 ^ lx) * 16));
    const unsigned raB1 = (unsigned)((wm * 64 + lrow) * 128 + (((4 | l47) ^ lx) * 16));
    const unsigned rbB0 = (unsigned)(16384 + (wn * 64 + lrow) * 128 + ((l47 ^ lx) * 16));
    const unsigned rbB1 = (unsigned)(16384 + (wn * 64 + lrow) * 128 + (((4 | l47) ^ lx) * 16));

    float fA[4][8]; int qB[4][8]; float sB[4];
    auto load_s = [&]() {
        #pragma unroll
        for (int j = 0; j < 4; ++j) {
            float4 a0 = ((const float4*)aSrcF[j])[0];
            float4 a1 = ((const float4*)aSrcF[j])[1];
            fA[j][0] = a0.x; fA[j][1] = a0.y; fA[j][2] = a0.z; fA[j][3] = a0.w;
            fA[j][4] = a1.x; fA[j][5] = a1.y; fA[j][6] = a1.z; fA[j][7] = a1.w;
            aSrcF[j] += 64;
            int4 b0 = ((const int4*)bSrcQ[j])[0];
            int4 b1 = ((const int4*)bSrcQ[j])[1];
            qB[j][0] = b0.x; qB[j][1] = b0.y; qB[j][2] = b0.z; qB[j][3] = b0.w;
            qB[j][4] = b1.x; qB[j][5] = b1.y; qB[j][6] = b1.z; qB[j][7] = b1.w;
            bSrcQ[j] += 64;
            sB[j] = *bSrcS[j]; bSrcS[j] += 2;
        }
    };
    auto write_s = [&](int bsel) {
        #pragma unroll
        for (int j = 0; j < 4; ++j) {
            u16x8 va, vb;
            #pragma unroll
            for (int e = 0; e < 8; ++e) va[e] = f2bf(fA[j][e]);
            #pragma unroll
            for (int e = 0; e < 8; ++e) vb[e] = f2bf((float)qB[j][e] * sB[j]);
            *(u16x8*)(&smem[bsel * 32768 + (w * 4 + j) * 1024 + l * 16]) = va;
            *(u16x8*)(&smem[bsel * 32768 + 16384 + (w * 4 + j) * 1024 + l * 16]) = vb;
        }
    };

    f32x4 acc[4][4] = {};
    load_s(); write_s(0);
    __syncthreads();
    int bsel = 0;
    for (int kt = 0; kt < 64; ++kt) {
        const bool pre = (kt + 1 < 64);
        if (pre) load_s();
        const unsigned boff = (unsigned)(bsel * 32768);
        #pragma unroll
        for (int kk = 0; kk < 2; ++kk) {
            bf16x8 av[4], bv[4];
            const unsigned ra = (kk ? raB1 : raB0) + boff;
            const unsigned rb = (kk ? rbB1 : rbB0) + boff;
            #pragma unroll
            for (int mf = 0; mf < 4; ++mf) av[mf] = *(const bf16x8*)(&smem[ra + mf * 2048]);
            #pragma unroll
            for (int nf = 0; nf < 4; ++nf) bv[nf] = *(const bf16x8*)(&smem[rb + nf * 2048]);
            #pragma unroll
            for (int mf = 0; mf < 4; ++mf)
                #pragma unroll
                for (int nf = 0; nf < 4; ++nf)
                    acc[mf][nf] = __builtin_amdgcn_mfma_f32_16x16x32_bf16(
                        av[mf], bv[nf], acc[mf][nf], 0, 0, 0);
        }
        if (pre) write_s(bsel ^ 1);
        __syncthreads();
        bsel ^= 1;
    }
    const int orow0 = rowA0 + wm * 64 + l47 * 4;
    const int ocol0 = colB0 + wn * 64 + lrow;
    #pragma unroll
    for (int nf = 0; nf < 4; ++nf) {
        const float bv = bias[ocol0 + nf * 16];
        #pragma unroll
        for (int mf = 0; mf < 4; ++mf) {
            f32x4 v = acc[mf][nf];
            #pragma unroll
            for (int j = 0; j < 4; ++j)
                out[(size_t)(orow0 + mf * 16 + j) * N_DIM + (ocol0 + nf * 16)] = v[j] + bv;
        }
    }
}

extern "C" void kernel_launch(void* const* d_in, const int* in_sizes, int n_in,
                              void* d_out, int out_size, void* d_ws, size_t ws_size,
                              hipStream_t stream) {
    const float* x    = (const float*)d_in[0];
    const int*   qw   = (const int*)d_in[1];
    const float* sc   = (const float*)d_in[2];
    const float* bias = (const float*)d_in[3];
    float* out = (float*)d_out;

    const size_t need = ((size_t)M_DIM * K_DIM + (size_t)N_DIM * K_DIM) * 2;  // 160 MiB
    if (ws_size >= need) {
        unsigned short* xb = (unsigned short*)d_ws;
        unsigned short* wb = xb + (size_t)M_DIM * K_DIM;
        cvt_x_kernel<<<dim3(2048), dim3(256), 0, stream>>>(x, xb);
        dequant_w_kernel<<<dim3(4096), dim3(256), 0, stream>>>(qw, sc, wb);
        gemm256<<<dim3(64, 16), dim3(512), 0, stream>>>(xb, wb, bias, out);
    } else {
        gemm_fused<<<dim3(128, 32), dim3(256), 0, stream>>>(x, qw, sc, bias, out);
    }
}